// Round 1
// baseline (582.231 us; speedup 1.0000x reference)
//
#include <hip/hip_runtime.h>

#define N_NODES 50000
#define N_EDGES 800000

// ---------------- CSR construction ----------------

__global__ void zero_i32(int* __restrict__ p, int n) {
  int i = blockIdx.x * blockDim.x + threadIdx.x;
  if (i < n) p[i] = 0;
}

__global__ void hist_kernel(const int* __restrict__ dst, int* __restrict__ cnt, int E) {
  int e = blockIdx.x * blockDim.x + threadIdx.x;
  if (e < E) atomicAdd(&cnt[dst[e]], 1);
}

// Single-block exclusive scan over n counts -> rowptr[0..n], cursor copy.
__global__ void scan_kernel(const int* __restrict__ cnt, int* __restrict__ rowptr,
                            int* __restrict__ cursor, int n) {
  const int T = 1024;
  int tid = threadIdx.x;
  int C = (n + T - 1) / T;          // elements per thread (49)
  int lo = tid * C;
  int hi = lo + C; if (hi > n) hi = n;
  int s = 0;
  for (int i = lo; i < hi; i++) s += cnt[i];

  int lane = tid & 63, wid = tid >> 6;
  int incl = s;
  #pragma unroll
  for (int off = 1; off < 64; off <<= 1) {
    int t = __shfl_up(incl, off);
    if (lane >= off) incl += t;
  }
  __shared__ int wsum[16];
  if (lane == 63) wsum[wid] = incl;
  __syncthreads();
  if (wid == 0) {
    int v = (lane < 16) ? wsum[lane] : 0;
    #pragma unroll
    for (int off = 1; off < 16; off <<= 1) {
      int t = __shfl_up(v, off);
      if (lane >= off) v += t;
    }
    if (lane < 16) wsum[lane] = v;
  }
  __syncthreads();
  int waveoff = (wid > 0) ? wsum[wid - 1] : 0;
  int run = waveoff + incl - s;      // exclusive prefix of this thread's chunk
  for (int i = lo; i < hi; i++) {
    rowptr[i] = run;
    cursor[i] = run;
    run += cnt[i];
  }
  if (tid == 0) rowptr[n] = wsum[15];
}

__global__ void fill_kernel(const int* __restrict__ src, const int* __restrict__ dst,
                            int* __restrict__ cursor, int* __restrict__ csr, int E) {
  int e = blockIdx.x * blockDim.x + threadIdx.x;
  if (e < E) {
    int p = atomicAdd(&cursor[dst[e]], 1);
    csr[p] = src[e];
  }
}

// ---------------- mean aggregation (gather form) ----------------
// One block per node, thread = feature. h rows are D*4 bytes contiguous.
template <int D>
__global__ void agg_kernel(const float* __restrict__ h, const int* __restrict__ rowptr,
                           const int* __restrict__ csr, float* __restrict__ mean) {
  int node = blockIdx.x;
  int f = threadIdx.x;
  int lo = rowptr[node], hi = rowptr[node + 1];
  float s = 0.f;
  int e = lo;
  for (; e + 3 < hi; e += 4) {
    int s0 = csr[e], s1 = csr[e + 1], s2 = csr[e + 2], s3 = csr[e + 3];
    s += h[s0 * D + f] + h[s1 * D + f] + h[s2 * D + f] + h[s3 * D + f];
  }
  for (; e < hi; e++) s += h[csr[e] * D + f];
  int deg = hi - lo;
  float inv = (deg > 0) ? 1.f / (float)deg : 0.f;
  mean[node * D + f] = s * inv;
}

// ---------------- fused dual GEMM + bias + relu ----------------
// out[n][j] = relu( mean[n]·Wl[:,j] + x[n]·Wr[:,j] + b[j] )
// Wl,Wr are [K][J] row-major. 256 threads; 32 rows/block staged in LDS.
template <int K, int J>
__global__ __launch_bounds__(256) void gemm_kernel(
    const float* __restrict__ mean, const float* __restrict__ x,
    const float* __restrict__ Wl, const float* __restrict__ Wr,
    const float* __restrict__ bias, float* __restrict__ out, int n) {
  constexpr int R = 32;            // rows per block
  constexpr int G = 256 / J;       // row groups
  constexpr int RT = R / G;        // rows per thread
  __shared__ __align__(16) float sm[R][K];
  __shared__ __align__(16) float sx[R][K];
  int tid = threadIdx.x;
  int j = tid % J, g = tid / J;
  int row0 = blockIdx.x * R;

  for (int idx = tid * 4; idx < R * K; idx += 256 * 4) {
    int r = idx / K, c = idx % K;
    int grow = row0 + r;
    float4 vm = make_float4(0.f, 0.f, 0.f, 0.f), vx = vm;
    if (grow < n) {
      vm = *(const float4*)(mean + grow * K + c);
      vx = *(const float4*)(x + grow * K + c);
    }
    *(float4*)(&sm[r][c]) = vm;
    *(float4*)(&sx[r][c]) = vx;
  }
  __syncthreads();

  float acc[RT];
  #pragma unroll
  for (int r = 0; r < RT; r++) acc[r] = 0.f;

  for (int k = 0; k < K; k += 4) {
    float wl0 = Wl[(k + 0) * J + j], wl1 = Wl[(k + 1) * J + j],
          wl2 = Wl[(k + 2) * J + j], wl3 = Wl[(k + 3) * J + j];
    float wr0 = Wr[(k + 0) * J + j], wr1 = Wr[(k + 1) * J + j],
          wr2 = Wr[(k + 2) * J + j], wr3 = Wr[(k + 3) * J + j];
    #pragma unroll
    for (int r = 0; r < RT; r++) {
      int rr = g * RT + r;
      float4 m4 = *(const float4*)(&sm[rr][k]);
      float4 x4 = *(const float4*)(&sx[rr][k]);
      acc[r] += m4.x * wl0 + m4.y * wl1 + m4.z * wl2 + m4.w * wl3
              + x4.x * wr0 + x4.y * wr1 + x4.z * wr2 + x4.w * wr3;
    }
  }

  float bv = bias[j];
  #pragma unroll
  for (int r = 0; r < RT; r++) {
    int grow = row0 + g * RT + r;
    if (grow < n) {
      float v = acc[r] + bv;
      out[grow * J + j] = v > 0.f ? v : 0.f;
    }
  }
}

// ---------------- final linear head: [N,64] @ [64,2] + bc ----------------
__global__ void final_kernel(const float* __restrict__ h, const float* __restrict__ Wc,
                             const float* __restrict__ bc, float* __restrict__ out, int n) {
  int node = blockIdx.x * 4 + (threadIdx.x >> 6);
  int k = threadIdx.x & 63;
  if (node >= n) return;
  float v = h[node * 64 + k];
  float p0 = v * Wc[k * 2 + 0];
  float p1 = v * Wc[k * 2 + 1];
  #pragma unroll
  for (int off = 32; off >= 1; off >>= 1) {
    p0 += __shfl_down(p0, off);
    p1 += __shfl_down(p1, off);
  }
  if (k == 0) {
    out[node * 2 + 0] = p0 + bc[0];
    out[node * 2 + 1] = p1 + bc[1];
  }
}

extern "C" void kernel_launch(void* const* d_in, const int* in_sizes, int n_in,
                              void* d_out, int out_size, void* d_ws, size_t ws_size,
                              hipStream_t stream) {
  const float* x   = (const float*)d_in[0];
  const int*   ei  = (const int*)d_in[1];
  const float* Wl1 = (const float*)d_in[2];
  const float* Wr1 = (const float*)d_in[3];
  const float* b1  = (const float*)d_in[4];
  const float* Wl2 = (const float*)d_in[5];
  const float* Wr2 = (const float*)d_in[6];
  const float* b2  = (const float*)d_in[7];
  const float* Wl3 = (const float*)d_in[8];
  const float* Wr3 = (const float*)d_in[9];
  const float* b3  = (const float*)d_in[10];
  const float* Wc  = (const float*)d_in[11];
  const float* bc  = (const float*)d_in[12];
  float* out = (float*)d_out;

  const int* src = ei;            // edge_index[0]
  const int* dst = ei + N_EDGES;  // edge_index[1]

  char* ws = (char*)d_ws;
  size_t off = 0;
  auto alloc = [&](size_t bytes) -> void* {
    void* p = ws + off;
    off += (bytes + 255) & ~(size_t)255;
    return p;
  };
  int*   rowptr = (int*)alloc((N_NODES + 1) * sizeof(int));
  int*   cnt    = (int*)alloc(N_NODES * sizeof(int));
  int*   cursor = (int*)alloc(N_NODES * sizeof(int));
  int*   csr    = (int*)alloc(N_EDGES * sizeof(int));
  float* meanb  = (float*)alloc((size_t)N_NODES * 128 * sizeof(float));
  float* hA     = (float*)alloc((size_t)N_NODES * 128 * sizeof(float));
  float* hB     = (float*)alloc((size_t)N_NODES * 128 * sizeof(float));
  (void)ws_size; (void)n_in; (void)in_sizes; (void)out_size;

  // CSR build (deterministic counts; within-node order is atomic-arrival order,
  // which only perturbs f32 sum rounding at ~ulp level).
  zero_i32<<<(N_NODES + 255) / 256, 256, 0, stream>>>(cnt, N_NODES);
  hist_kernel<<<(N_EDGES + 255) / 256, 256, 0, stream>>>(dst, cnt, N_EDGES);
  scan_kernel<<<1, 1024, 0, stream>>>(cnt, rowptr, cursor, N_NODES);
  fill_kernel<<<(N_EDGES + 255) / 256, 256, 0, stream>>>(src, dst, cursor, csr, N_EDGES);

  const int gemm_grid = (N_NODES + 31) / 32;

  // layer 1: 96 -> 128
  agg_kernel<96><<<N_NODES, 96, 0, stream>>>(x, rowptr, csr, meanb);
  gemm_kernel<96, 128><<<gemm_grid, 256, 0, stream>>>(meanb, x, Wl1, Wr1, b1, hA, N_NODES);
  // layer 2: 128 -> 128
  agg_kernel<128><<<N_NODES, 128, 0, stream>>>(hA, rowptr, csr, meanb);
  gemm_kernel<128, 128><<<gemm_grid, 256, 0, stream>>>(meanb, hA, Wl2, Wr2, b2, hB, N_NODES);
  // layer 3: 128 -> 64
  agg_kernel<128><<<N_NODES, 128, 0, stream>>>(hB, rowptr, csr, meanb);
  gemm_kernel<128, 64><<<gemm_grid, 256, 0, stream>>>(meanb, hB, Wl3, Wr3, b3, hA, N_NODES);
  // head: 64 -> 2
  final_kernel<<<(N_NODES + 3) / 4, 256, 0, stream>>>(hA, Wc, bc, out, N_NODES);
}

// Round 2
// 465.895 us; speedup vs baseline: 1.2497x; 1.2497x over previous
//
#include <hip/hip_runtime.h>

#define N_NODES 50000
#define N_EDGES 800000
#define SCAN_NB ((N_NODES + 255) / 256)   // 196 blocks

// ---------------- CSR construction ----------------

__global__ void zero_i32(int* __restrict__ p, int n) {
  int i = blockIdx.x * blockDim.x + threadIdx.x;
  if (i < n) p[i] = 0;
}

__global__ void hist_kernel(const int* __restrict__ dst, int* __restrict__ cnt, int E) {
  int e = blockIdx.x * blockDim.x + threadIdx.x;
  if (e < E) atomicAdd(&cnt[dst[e]], 1);
}

// exclusive scan of v across 256 threads; also returns block total
__device__ __forceinline__ int block_excl_scan_256(int v, int tid, int* tot_out) {
  __shared__ int ws[4];
  int lane = tid & 63, wid = tid >> 6;
  int incl = v;
  #pragma unroll
  for (int off = 1; off < 64; off <<= 1) {
    int t = __shfl_up(incl, off);
    if (lane >= off) incl += t;
  }
  if (lane == 63) ws[wid] = incl;
  __syncthreads();
  int woff = 0;
  #pragma unroll
  for (int w = 0; w < 4; w++) woff += (w < wid) ? ws[w] : 0;
  *tot_out = ws[0] + ws[1] + ws[2] + ws[3];
  return woff + incl - v;
}

// stage A: per-block exclusive scan of cnt -> rowptr (pre-offset), block totals
__global__ __launch_bounds__(256) void scanA(const int* __restrict__ cnt,
                                             int* __restrict__ rowptr,
                                             int* __restrict__ blocksum, int n) {
  int i = blockIdx.x * 256 + threadIdx.x;
  int v = (i < n) ? cnt[i] : 0;
  int tot;
  int excl = block_excl_scan_256(v, threadIdx.x, &tot);
  if (i < n) rowptr[i] = excl;
  if (threadIdx.x == 0) blocksum[blockIdx.x] = tot;
}

// stage B: single block scans the <=256 block totals
__global__ __launch_bounds__(256) void scanB(const int* __restrict__ blocksum,
                                             int* __restrict__ blockoff,
                                             int* __restrict__ rowptr, int nb, int n) {
  int tid = threadIdx.x;
  int v = (tid < nb) ? blocksum[tid] : 0;
  int tot;
  int excl = block_excl_scan_256(v, tid, &tot);
  if (tid < nb) blockoff[tid] = excl;
  if (tid == 0) rowptr[n] = tot;
}

// stage C: add block offsets, materialize cursor
__global__ __launch_bounds__(256) void scanC(int* __restrict__ rowptr,
                                             const int* __restrict__ blockoff,
                                             int* __restrict__ cursor, int n) {
  int i = blockIdx.x * 256 + threadIdx.x;
  if (i < n) {
    int r = rowptr[i] + blockoff[blockIdx.x];
    rowptr[i] = r;
    cursor[i] = r;
  }
}

__global__ void fill_kernel(const int* __restrict__ src, const int* __restrict__ dst,
                            int* __restrict__ cursor, int* __restrict__ csr, int E) {
  int e = blockIdx.x * blockDim.x + threadIdx.x;
  if (e < E) {
    int p = atomicAdd(&cursor[dst[e]], 1);
    csr[p] = src[e];
  }
}

// ---------------- mean aggregation (gather form) ----------------
// 32 lanes per node, 8 nodes per 256-thread block. Lane owns D/32 contiguous
// floats -> float4 gathers for D=128 (one 512B coalesced row per edge).
template <int D>
__global__ __launch_bounds__(256) void agg_kernel(const float* __restrict__ h,
                                                  const int* __restrict__ rowptr,
                                                  const int* __restrict__ csr,
                                                  float* __restrict__ mean, int n) {
  constexpr int FPL = D / 32;   // floats per lane: 3 (D=96) or 4 (D=128)
  int node = blockIdx.x * 8 + (threadIdx.x >> 5);
  int lane = threadIdx.x & 31;
  if (node >= n) return;
  int lo = rowptr[node], hi = rowptr[node + 1];

  float s[FPL];
  #pragma unroll
  for (int f = 0; f < FPL; f++) s[f] = 0.f;

  auto accum = [&](int srcn) {
    const float* row = h + (size_t)srcn * D + lane * FPL;
    if constexpr (FPL == 4) {
      float4 v = *(const float4*)row;
      s[0] += v.x; s[1] += v.y; s[2] += v.z; s[3] += v.w;
    } else {
      #pragma unroll
      for (int f = 0; f < FPL; f++) s[f] += row[f];
    }
  };

  int e = lo;
  for (; e + 3 < hi; e += 4) {
    int a = csr[e], b = csr[e + 1], c = csr[e + 2], d = csr[e + 3];
    accum(a); accum(b); accum(c); accum(d);
  }
  for (; e < hi; e++) accum(csr[e]);

  int deg = hi - lo;
  float inv = (deg > 0) ? 1.f / (float)deg : 0.f;
  float* orow = mean + (size_t)node * D + lane * FPL;
  if constexpr (FPL == 4) {
    float4 o = make_float4(s[0] * inv, s[1] * inv, s[2] * inv, s[3] * inv);
    *(float4*)orow = o;
  } else {
    #pragma unroll
    for (int f = 0; f < FPL; f++) orow[f] = s[f] * inv;
  }
}

// ---------------- fused dual GEMM + bias + relu ----------------
// out[n][j] = relu( mean[n]·Wl[:,j] + x[n]·Wr[:,j] + b[j] )
template <int K, int J>
__global__ __launch_bounds__(256) void gemm_kernel(
    const float* __restrict__ mean, const float* __restrict__ x,
    const float* __restrict__ Wl, const float* __restrict__ Wr,
    const float* __restrict__ bias, float* __restrict__ out, int n) {
  constexpr int R = 32;            // rows per block
  constexpr int G = 256 / J;       // row groups
  constexpr int RT = R / G;        // rows per thread
  __shared__ __align__(16) float sm[R][K];
  __shared__ __align__(16) float sx[R][K];
  int tid = threadIdx.x;
  int j = tid % J, g = tid / J;
  int row0 = blockIdx.x * R;

  for (int idx = tid * 4; idx < R * K; idx += 256 * 4) {
    int r = idx / K, c = idx % K;
    int grow = row0 + r;
    float4 vm = make_float4(0.f, 0.f, 0.f, 0.f), vx = vm;
    if (grow < n) {
      vm = *(const float4*)(mean + (size_t)grow * K + c);
      vx = *(const float4*)(x + (size_t)grow * K + c);
    }
    *(float4*)(&sm[r][c]) = vm;
    *(float4*)(&sx[r][c]) = vx;
  }
  __syncthreads();

  float acc[RT];
  #pragma unroll
  for (int r = 0; r < RT; r++) acc[r] = 0.f;

  for (int k = 0; k < K; k += 4) {
    float wl0 = Wl[(k + 0) * J + j], wl1 = Wl[(k + 1) * J + j],
          wl2 = Wl[(k + 2) * J + j], wl3 = Wl[(k + 3) * J + j];
    float wr0 = Wr[(k + 0) * J + j], wr1 = Wr[(k + 1) * J + j],
          wr2 = Wr[(k + 2) * J + j], wr3 = Wr[(k + 3) * J + j];
    #pragma unroll
    for (int r = 0; r < RT; r++) {
      int rr = g * RT + r;
      float4 m4 = *(const float4*)(&sm[rr][k]);
      float4 x4 = *(const float4*)(&sx[rr][k]);
      acc[r] += m4.x * wl0 + m4.y * wl1 + m4.z * wl2 + m4.w * wl3
              + x4.x * wr0 + x4.y * wr1 + x4.z * wr2 + x4.w * wr3;
    }
  }

  float bv = bias[j];
  #pragma unroll
  for (int r = 0; r < RT; r++) {
    int grow = row0 + g * RT + r;
    if (grow < n) {
      float v = acc[r] + bv;
      out[(size_t)grow * J + j] = v > 0.f ? v : 0.f;
    }
  }
}

// ---------------- final linear head: [N,64] @ [64,2] + bc ----------------
__global__ void final_kernel(const float* __restrict__ h, const float* __restrict__ Wc,
                             const float* __restrict__ bc, float* __restrict__ out, int n) {
  int node = blockIdx.x * 4 + (threadIdx.x >> 6);
  int k = threadIdx.x & 63;
  if (node >= n) return;
  float v = h[node * 64 + k];
  float p0 = v * Wc[k * 2 + 0];
  float p1 = v * Wc[k * 2 + 1];
  #pragma unroll
  for (int off = 32; off >= 1; off >>= 1) {
    p0 += __shfl_down(p0, off);
    p1 += __shfl_down(p1, off);
  }
  if (k == 0) {
    out[node * 2 + 0] = p0 + bc[0];
    out[node * 2 + 1] = p1 + bc[1];
  }
}

extern "C" void kernel_launch(void* const* d_in, const int* in_sizes, int n_in,
                              void* d_out, int out_size, void* d_ws, size_t ws_size,
                              hipStream_t stream) {
  const float* x   = (const float*)d_in[0];
  const int*   ei  = (const int*)d_in[1];
  const float* Wl1 = (const float*)d_in[2];
  const float* Wr1 = (const float*)d_in[3];
  const float* b1  = (const float*)d_in[4];
  const float* Wl2 = (const float*)d_in[5];
  const float* Wr2 = (const float*)d_in[6];
  const float* b2  = (const float*)d_in[7];
  const float* Wl3 = (const float*)d_in[8];
  const float* Wr3 = (const float*)d_in[9];
  const float* b3  = (const float*)d_in[10];
  const float* Wc  = (const float*)d_in[11];
  const float* bc  = (const float*)d_in[12];
  float* out = (float*)d_out;

  const int* src = ei;            // edge_index[0]
  const int* dst = ei + N_EDGES;  // edge_index[1]

  char* ws = (char*)d_ws;
  size_t off = 0;
  auto alloc = [&](size_t bytes) -> void* {
    void* p = ws + off;
    off += (bytes + 255) & ~(size_t)255;
    return p;
  };
  int*   rowptr  = (int*)alloc((N_NODES + 1) * sizeof(int));
  int*   cnt     = (int*)alloc(N_NODES * sizeof(int));
  int*   cursor  = (int*)alloc(N_NODES * sizeof(int));
  int*   csr     = (int*)alloc(N_EDGES * sizeof(int));
  int*   blocksum= (int*)alloc(256 * sizeof(int));
  int*   blockoff= (int*)alloc(256 * sizeof(int));
  float* meanb   = (float*)alloc((size_t)N_NODES * 128 * sizeof(float));
  float* hA      = (float*)alloc((size_t)N_NODES * 128 * sizeof(float));
  float* hB      = (float*)alloc((size_t)N_NODES * 128 * sizeof(float));
  (void)ws_size; (void)n_in; (void)in_sizes; (void)out_size;

  // CSR build
  zero_i32<<<(N_NODES + 255) / 256, 256, 0, stream>>>(cnt, N_NODES);
  hist_kernel<<<(N_EDGES + 255) / 256, 256, 0, stream>>>(dst, cnt, N_EDGES);
  scanA<<<SCAN_NB, 256, 0, stream>>>(cnt, rowptr, blocksum, N_NODES);
  scanB<<<1, 256, 0, stream>>>(blocksum, blockoff, rowptr, SCAN_NB, N_NODES);
  scanC<<<SCAN_NB, 256, 0, stream>>>(rowptr, blockoff, cursor, N_NODES);
  fill_kernel<<<(N_EDGES + 255) / 256, 256, 0, stream>>>(src, dst, cursor, csr, N_EDGES);

  const int gemm_grid = (N_NODES + 31) / 32;
  const int agg_grid  = (N_NODES + 7) / 8;

  // layer 1: 96 -> 128
  agg_kernel<96><<<agg_grid, 256, 0, stream>>>(x, rowptr, csr, meanb, N_NODES);
  gemm_kernel<96, 128><<<gemm_grid, 256, 0, stream>>>(meanb, x, Wl1, Wr1, b1, hA, N_NODES);
  // layer 2: 128 -> 128
  agg_kernel<128><<<agg_grid, 256, 0, stream>>>(hA, rowptr, csr, meanb, N_NODES);
  gemm_kernel<128, 128><<<gemm_grid, 256, 0, stream>>>(meanb, hA, Wl2, Wr2, b2, hB, N_NODES);
  // layer 3: 128 -> 64
  agg_kernel<128><<<agg_grid, 256, 0, stream>>>(hB, rowptr, csr, meanb, N_NODES);
  gemm_kernel<128, 64><<<gemm_grid, 256, 0, stream>>>(meanb, hB, Wl3, Wr3, b3, hA, N_NODES);
  // head: 64 -> 2
  final_kernel<<<(N_NODES + 3) / 4, 256, 0, stream>>>(hA, Wc, bc, out, N_NODES);
}

// Round 3
// 241.012 us; speedup vs baseline: 2.4158x; 1.9331x over previous
//
#include <hip/hip_runtime.h>

#define N_NODES 50000
#define N_EDGES 800000
#define SCAN_NB ((N_NODES + 255) / 256)

typedef __attribute__((ext_vector_type(8))) short short8;
typedef __attribute__((ext_vector_type(8))) unsigned short ushort8;
typedef __attribute__((ext_vector_type(4))) float f32x4;

__device__ __forceinline__ float bf2f(unsigned short u) {
  unsigned int x = ((unsigned int)u) << 16;
  return __builtin_bit_cast(float, x);
}
__device__ __forceinline__ unsigned short f2bf(float f) {
  unsigned int x = __builtin_bit_cast(unsigned int, f);
  unsigned int r = x + 0x7FFFu + ((x >> 16) & 1u);
  return (unsigned short)(r >> 16);
}

// ---------------- CSR construction ----------------

__global__ void zero_i32(int* __restrict__ p, int n) {
  int i = blockIdx.x * blockDim.x + threadIdx.x;
  if (i < n) p[i] = 0;
}

__global__ void hist_kernel(const int* __restrict__ dst, int* __restrict__ cnt, int E) {
  int e = blockIdx.x * blockDim.x + threadIdx.x;
  if (e < E) atomicAdd(&cnt[dst[e]], 1);
}

__device__ __forceinline__ int block_excl_scan_256(int v, int tid, int* tot_out) {
  __shared__ int ws[4];
  int lane = tid & 63, wid = tid >> 6;
  int incl = v;
  #pragma unroll
  for (int off = 1; off < 64; off <<= 1) {
    int t = __shfl_up(incl, off);
    if (lane >= off) incl += t;
  }
  if (lane == 63) ws[wid] = incl;
  __syncthreads();
  int woff = 0;
  #pragma unroll
  for (int w = 0; w < 4; w++) woff += (w < wid) ? ws[w] : 0;
  *tot_out = ws[0] + ws[1] + ws[2] + ws[3];
  return woff + incl - v;
}

__global__ __launch_bounds__(256) void scanA(const int* __restrict__ cnt,
                                             int* __restrict__ rowptr,
                                             int* __restrict__ blocksum, int n) {
  int i = blockIdx.x * 256 + threadIdx.x;
  int v = (i < n) ? cnt[i] : 0;
  int tot;
  int excl = block_excl_scan_256(v, threadIdx.x, &tot);
  if (i < n) rowptr[i] = excl;
  if (threadIdx.x == 0) blocksum[blockIdx.x] = tot;
}

__global__ __launch_bounds__(256) void scanB(const int* __restrict__ blocksum,
                                             int* __restrict__ blockoff,
                                             int* __restrict__ rowptr, int nb, int n) {
  int tid = threadIdx.x;
  int v = (tid < nb) ? blocksum[tid] : 0;
  int tot;
  int excl = block_excl_scan_256(v, tid, &tot);
  if (tid < nb) blockoff[tid] = excl;
  if (tid == 0) rowptr[n] = tot;
}

__global__ __launch_bounds__(256) void scanC(int* __restrict__ rowptr,
                                             const int* __restrict__ blockoff,
                                             int* __restrict__ cursor, int n) {
  int i = blockIdx.x * 256 + threadIdx.x;
  if (i < n) {
    int r = rowptr[i] + blockoff[blockIdx.x];
    rowptr[i] = r;
    cursor[i] = r;
  }
}

__global__ void fill_kernel(const int* __restrict__ src, const int* __restrict__ dst,
                            int* __restrict__ cursor, int* __restrict__ csr, int E) {
  int e = blockIdx.x * blockDim.x + threadIdx.x;
  if (e < E) {
    int p = atomicAdd(&cursor[dst[e]], 1);
    csr[p] = src[e];
  }
}

// ---------------- conversions ----------------

// f32 -> bf16, 4 elements per thread
__global__ void cvt_x_kernel(const float* __restrict__ x, ushort* __restrict__ xb, int n4) {
  int i = blockIdx.x * blockDim.x + threadIdx.x;
  if (i >= n4) return;
  float4 v = *(const float4*)(x + i * 4);
  ushort u0 = f2bf(v.x), u1 = f2bf(v.y), u2 = f2bf(v.z), u3 = f2bf(v.w);
  ushort4 o = make_ushort4(u0, u1, u2, u3);
  *(ushort4*)(xb + i * 4) = o;
}

// pack [Wl | Wr] (each [K][J2] f32 row-major) into bf16 MFMA-swizzled layout:
// wcat[kk8][j][i] = W[kk8*8+i][j],  j in [0,2*J2)
__global__ void pack_w(const float* __restrict__ Wl, const float* __restrict__ Wr,
                       ushort* __restrict__ wcat, int K, int J2) {
  int idx = blockIdx.x * 256 + threadIdx.x;
  int Jcat = 2 * J2;
  int total = (K / 8) * Jcat;
  if (idx >= total) return;
  int kk8 = idx / Jcat, j = idx % Jcat;
  const float* W = (j < J2) ? Wl : Wr;
  int jj = (j < J2) ? j : j - J2;
  ushort8 v;
  #pragma unroll
  for (int i = 0; i < 8; i++) v[i] = f2bf(W[(kk8 * 8 + i) * J2 + jj]);
  *(ushort8*)(wcat + (size_t)idx * 8) = v;
}

// ---------------- bf16 MFMA GEMM: t = hb @ [Wl|Wr] ----------------
// hb: [n][K] bf16. wcat: [K/8][Jcat][8] bf16 (pre-swizzled). Outputs split:
// tl = cols [0,J2), tr = cols [J2,2*J2), both [n][J2] bf16.
template <int K, int J2>
__global__ __launch_bounds__(256) void gemm_mfma(
    const ushort* __restrict__ hb, const ushort* __restrict__ wcat,
    ushort* __restrict__ tl, ushort* __restrict__ tr, int n) {
  constexpr int Jcat = 2 * J2;
  constexpr int NT = Jcat / 16;     // 16-col tiles
  constexpr int KS = K / 32;        // k-steps
  constexpr int BM = 128;           // rows per block
  constexpr int LDS_US = (BM * Jcat > K * Jcat) ? BM * Jcat : K * Jcat;
  __shared__ ushort lds[LDS_US];

  int tid = threadIdx.x;
  int wid = tid >> 6, lane = tid & 63;
  int row0 = blockIdx.x * BM;

  // stage weights into LDS (contiguous copy; layout already MFMA-friendly)
  constexpr int WCH = K * Jcat / 8;  // 16B chunks
  for (int c = tid; c < WCH; c += 256) {
    *(ushort8*)(lds + c * 8) = *(const ushort8*)(wcat + (size_t)c * 8);
  }
  __syncthreads();

  int rg = lane >> 4, lc = lane & 15;
  int r0 = row0 + wid * 32 + lc;    // m-tile 0 row
  int r1 = r0 + 16;                 // m-tile 1 row
  long ar0 = (long)min(r0, n - 1) * K;
  long ar1 = (long)min(r1, n - 1) * K;

  f32x4 acc[2][NT];
  #pragma unroll
  for (int mt = 0; mt < 2; mt++)
    #pragma unroll
    for (int jt = 0; jt < NT; jt++) acc[mt][jt] = (f32x4){0.f, 0.f, 0.f, 0.f};

  #pragma unroll
  for (int ks = 0; ks < KS; ks++) {
    int koff = ks * 32 + rg * 8;
    short8 a0 = *(const short8*)(hb + ar0 + koff);
    short8 a1 = *(const short8*)(hb + ar1 + koff);
    int kk8 = ks * 4 + rg;
    #pragma unroll
    for (int jt = 0; jt < NT; jt++) {
      short8 b = *(const short8*)(lds + ((size_t)kk8 * Jcat + jt * 16 + lc) * 8);
      acc[0][jt] = __builtin_amdgcn_mfma_f32_16x16x32_bf16(a0, b, acc[0][jt], 0, 0, 0);
      acc[1][jt] = __builtin_amdgcn_mfma_f32_16x16x32_bf16(a1, b, acc[1][jt], 0, 0, 0);
    }
  }
  __syncthreads();   // done with weights; reuse LDS for C transpose

  // C/D layout (m89): col = lane&15, row = (lane>>4)*4 + reg
  #pragma unroll
  for (int mt = 0; mt < 2; mt++) {
    int rbase = wid * 32 + mt * 16 + rg * 4;
    #pragma unroll
    for (int jt = 0; jt < NT; jt++) {
      int col = jt * 16 + lc;
      #pragma unroll
      for (int r = 0; r < 4; r++)
        lds[(size_t)(rbase + r) * Jcat + col] = f2bf(acc[mt][jt][r]);
    }
  }
  __syncthreads();

  // coalesced write-out, split into tl / tr
  constexpr int CPR = J2 / 8;       // 16B chunks per row per output
  for (int i = tid; i < BM * 2 * CPR; i += 256) {
    int row = i / (2 * CPR), cc = i % (2 * CPR);
    int grow = row0 + row;
    if (grow < n) {
      ushort8 v = *(ushort8*)(lds + (size_t)row * Jcat + cc * 8);
      ushort* dstp = (cc < CPR) ? (tl + (size_t)grow * J2 + cc * 8)
                                : (tr + (size_t)grow * J2 + (size_t)(cc - CPR) * 8);
      *(ushort8*)dstp = v;
    }
  }
}

// ---------------- fused aggregate + bias + relu (J2=128) ----------------
// hout[node] = relu( mean_{s in N(node)} tl[s] + tr[node] + b ), bf16 out.
// 16 lanes per node, 16B (8 bf16) per lane.
__global__ __launch_bounds__(256) void agg_relu128(
    const ushort* __restrict__ tl, const ushort* __restrict__ tr,
    const float* __restrict__ bias,
    const int* __restrict__ rowptr, const int* __restrict__ csr,
    ushort* __restrict__ hout, int n) {
  int node = blockIdx.x * 16 + (threadIdx.x >> 4);
  int lane = threadIdx.x & 15;
  if (node >= n) return;
  int lo = rowptr[node], hi = rowptr[node + 1];

  float s[8];
  #pragma unroll
  for (int i = 0; i < 8; i++) s[i] = 0.f;

  int e = lo;
  for (; e + 1 < hi; e += 2) {
    int i0 = csr[e], i1 = csr[e + 1];
    ushort8 v0 = *(const ushort8*)(tl + (size_t)i0 * 128 + lane * 8);
    ushort8 v1 = *(const ushort8*)(tl + (size_t)i1 * 128 + lane * 8);
    #pragma unroll
    for (int i = 0; i < 8; i++) s[i] += bf2f(v0[i]) + bf2f(v1[i]);
  }
  if (e < hi) {
    ushort8 v0 = *(const ushort8*)(tl + (size_t)csr[e] * 128 + lane * 8);
    #pragma unroll
    for (int i = 0; i < 8; i++) s[i] += bf2f(v0[i]);
  }

  int deg = hi - lo;
  float inv = (deg > 0) ? 1.f / (float)deg : 0.f;
  ushort8 tv = *(const ushort8*)(tr + (size_t)node * 128 + lane * 8);
  float4 b0 = *(const float4*)(bias + lane * 8);
  float4 b1 = *(const float4*)(bias + lane * 8 + 4);
  float bb[8] = {b0.x, b0.y, b0.z, b0.w, b1.x, b1.y, b1.z, b1.w};
  ushort8 o;
  #pragma unroll
  for (int i = 0; i < 8; i++) {
    float v = s[i] * inv + bf2f(tv[i]) + bb[i];
    o[i] = f2bf(v > 0.f ? v : 0.f);
  }
  *(ushort8*)(hout + (size_t)node * 128 + lane * 8) = o;
}

// ---------------- layer 3 aggregate + relu + head (J2=64) ----------------
// logits[node] = relu(mean(tl3)+tr3+b3) @ Wc + bc.  8 lanes per node.
__global__ __launch_bounds__(256) void agg_head(
    const ushort* __restrict__ tl, const ushort* __restrict__ tr,
    const float* __restrict__ bias, const float* __restrict__ Wc,
    const float* __restrict__ bc,
    const int* __restrict__ rowptr, const int* __restrict__ csr,
    float* __restrict__ out, int n) {
  int node = blockIdx.x * 32 + (threadIdx.x >> 3);
  int lane = threadIdx.x & 7;
  if (node >= n) return;
  int lo = rowptr[node], hi = rowptr[node + 1];

  float s[8];
  #pragma unroll
  for (int i = 0; i < 8; i++) s[i] = 0.f;

  int e = lo;
  for (; e + 1 < hi; e += 2) {
    int i0 = csr[e], i1 = csr[e + 1];
    ushort8 v0 = *(const ushort8*)(tl + (size_t)i0 * 64 + lane * 8);
    ushort8 v1 = *(const ushort8*)(tl + (size_t)i1 * 64 + lane * 8);
    #pragma unroll
    for (int i = 0; i < 8; i++) s[i] += bf2f(v0[i]) + bf2f(v1[i]);
  }
  if (e < hi) {
    ushort8 v0 = *(const ushort8*)(tl + (size_t)csr[e] * 64 + lane * 8);
    #pragma unroll
    for (int i = 0; i < 8; i++) s[i] += bf2f(v0[i]);
  }

  int deg = hi - lo;
  float inv = (deg > 0) ? 1.f / (float)deg : 0.f;
  ushort8 tv = *(const ushort8*)(tr + (size_t)node * 64 + lane * 8);
  float p0 = 0.f, p1 = 0.f;
  #pragma unroll
  for (int i = 0; i < 8; i++) {
    int k = lane * 8 + i;
    float v = s[i] * inv + bf2f(tv[i]) + bias[k];
    v = v > 0.f ? v : 0.f;
    p0 += v * Wc[k * 2 + 0];
    p1 += v * Wc[k * 2 + 1];
  }
  #pragma unroll
  for (int off = 1; off < 8; off <<= 1) {
    p0 += __shfl_xor(p0, off);
    p1 += __shfl_xor(p1, off);
  }
  if (lane == 0) {
    out[(size_t)node * 2 + 0] = p0 + bc[0];
    out[(size_t)node * 2 + 1] = p1 + bc[1];
  }
}

extern "C" void kernel_launch(void* const* d_in, const int* in_sizes, int n_in,
                              void* d_out, int out_size, void* d_ws, size_t ws_size,
                              hipStream_t stream) {
  const float* x   = (const float*)d_in[0];
  const int*   ei  = (const int*)d_in[1];
  const float* Wl1 = (const float*)d_in[2];
  const float* Wr1 = (const float*)d_in[3];
  const float* b1  = (const float*)d_in[4];
  const float* Wl2 = (const float*)d_in[5];
  const float* Wr2 = (const float*)d_in[6];
  const float* b2  = (const float*)d_in[7];
  const float* Wl3 = (const float*)d_in[8];
  const float* Wr3 = (const float*)d_in[9];
  const float* b3  = (const float*)d_in[10];
  const float* Wc  = (const float*)d_in[11];
  const float* bc  = (const float*)d_in[12];
  float* out = (float*)d_out;

  const int* src = ei;
  const int* dst = ei + N_EDGES;

  char* ws = (char*)d_ws;
  size_t off = 0;
  auto alloc = [&](size_t bytes) -> void* {
    void* p = ws + off;
    off += (bytes + 255) & ~(size_t)255;
    return p;
  };
  int*    rowptr   = (int*)alloc((N_NODES + 1) * sizeof(int));
  int*    cnt      = (int*)alloc(N_NODES * sizeof(int));
  int*    cursor   = (int*)alloc(N_NODES * sizeof(int));
  int*    csr      = (int*)alloc(N_EDGES * sizeof(int));
  int*    blocksum = (int*)alloc(256 * sizeof(int));
  int*    blockoff = (int*)alloc(256 * sizeof(int));
  ushort* xb       = (ushort*)alloc((size_t)N_NODES * 96 * 2);
  ushort* wcat1    = (ushort*)alloc((size_t)96 * 256 * 2);
  ushort* wcat2    = (ushort*)alloc((size_t)128 * 256 * 2);
  ushort* wcat3    = (ushort*)alloc((size_t)128 * 128 * 2);
  ushort* tl       = (ushort*)alloc((size_t)N_NODES * 128 * 2);
  ushort* tr       = (ushort*)alloc((size_t)N_NODES * 128 * 2);
  ushort* hA       = (ushort*)alloc((size_t)N_NODES * 128 * 2);
  ushort* hB       = (ushort*)alloc((size_t)N_NODES * 128 * 2);
  (void)ws_size; (void)n_in; (void)in_sizes; (void)out_size;

  // CSR build
  zero_i32<<<(N_NODES + 255) / 256, 256, 0, stream>>>(cnt, N_NODES);
  hist_kernel<<<(N_EDGES + 255) / 256, 256, 0, stream>>>(dst, cnt, N_EDGES);
  scanA<<<SCAN_NB, 256, 0, stream>>>(cnt, rowptr, blocksum, N_NODES);
  scanB<<<1, 256, 0, stream>>>(blocksum, blockoff, rowptr, SCAN_NB, N_NODES);
  scanC<<<SCAN_NB, 256, 0, stream>>>(rowptr, blockoff, cursor, N_NODES);
  fill_kernel<<<(N_EDGES + 255) / 256, 256, 0, stream>>>(src, dst, cursor, csr, N_EDGES);

  // conversions
  cvt_x_kernel<<<(N_NODES * 96 / 4 + 255) / 256, 256, 0, stream>>>(x, xb, N_NODES * 96 / 4);
  pack_w<<<(12 * 256 + 255) / 256, 256, 0, stream>>>(Wl1, Wr1, wcat1, 96, 128);
  pack_w<<<(16 * 256 + 255) / 256, 256, 0, stream>>>(Wl2, Wr2, wcat2, 128, 128);
  pack_w<<<(16 * 128 + 255) / 256, 256, 0, stream>>>(Wl3, Wr3, wcat3, 128, 64);

  const int gemm_grid = (N_NODES + 127) / 128;
  const int agg_grid  = (N_NODES + 15) / 16;
  const int head_grid = (N_NODES + 31) / 32;

  // layer 1: t = xb @ [Wl1|Wr1]; h1 = relu(mean(tl)+tr+b1)
  gemm_mfma<96, 128><<<gemm_grid, 256, 0, stream>>>(xb, wcat1, tl, tr, N_NODES);
  agg_relu128<<<agg_grid, 256, 0, stream>>>(tl, tr, b1, rowptr, csr, hA, N_NODES);
  // layer 2
  gemm_mfma<128, 128><<<gemm_grid, 256, 0, stream>>>(hA, wcat2, tl, tr, N_NODES);
  agg_relu128<<<agg_grid, 256, 0, stream>>>(tl, tr, b2, rowptr, csr, hB, N_NODES);
  // layer 3 + head
  gemm_mfma<128, 64><<<gemm_grid, 256, 0, stream>>>(hB, wcat3, tl, tr, N_NODES);
  agg_head<<<head_grid, 256, 0, stream>>>(tl, tr, b3, Wc, bc, rowptr, csr, out, N_NODES);
}

// Round 4
// 224.204 us; speedup vs baseline: 2.5969x; 1.0750x over previous
//
#include <hip/hip_runtime.h>

#define N_NODES 50000
#define N_EDGES 800000
#define SCAN_NB ((N_NODES + 255) / 256)
#define NRANGE 8
#define RANGE_SZ ((N_NODES + NRANGE - 1) / NRANGE)   // 6250
#define CSR_BLOCKS 2048

typedef __attribute__((ext_vector_type(8))) short short8;
typedef __attribute__((ext_vector_type(8))) unsigned short ushort8;
typedef __attribute__((ext_vector_type(4))) float f32x4;

__device__ __forceinline__ float bf2f(unsigned short u) {
  unsigned int x = ((unsigned int)u) << 16;
  return __builtin_bit_cast(float, x);
}
__device__ __forceinline__ unsigned short f2bf(float f) {
  unsigned int x = __builtin_bit_cast(unsigned int, f);
  unsigned int r = x + 0x7FFFu + ((x >> 16) & 1u);
  return (unsigned short)(r >> 16);
}

// ---------------- CSR construction ----------------

__global__ void zero_i32(int* __restrict__ p, int n) {
  int i = blockIdx.x * blockDim.x + threadIdx.x;
  if (i < n) p[i] = 0;
}

// XCD-range-partitioned histogram: block b handles node range (b&7)*6250..,
// which maps to XCD b&7 under round-robin dispatch -> atomic lines stay in
// one XCD's L2. Each range-set scans all edges (L2/L3-resident re-reads).
__global__ __launch_bounds__(256) void hist_ranged(const int* __restrict__ dst,
                                                   int* __restrict__ cnt, int E) {
  int r = blockIdx.x & (NRANGE - 1);
  int grp = blockIdx.x >> 3;
  int ngrp = gridDim.x >> 3;
  int lo = r * RANGE_SZ, hi = lo + RANGE_SZ;   // 50000 = 8*6250 exactly
  int stride = ngrp * 256;
  int e4n = E / 4;
  for (int i = grp * 256 + threadIdx.x; i < e4n; i += stride) {
    int4 d = *(const int4*)(dst + i * 4);
    if (d.x >= lo && d.x < hi) atomicAdd(&cnt[d.x], 1);
    if (d.y >= lo && d.y < hi) atomicAdd(&cnt[d.y], 1);
    if (d.z >= lo && d.z < hi) atomicAdd(&cnt[d.z], 1);
    if (d.w >= lo && d.w < hi) atomicAdd(&cnt[d.w], 1);
  }
}

__device__ __forceinline__ int block_excl_scan_256(int v, int tid, int* tot_out) {
  __shared__ int ws[4];
  int lane = tid & 63, wid = tid >> 6;
  int incl = v;
  #pragma unroll
  for (int off = 1; off < 64; off <<= 1) {
    int t = __shfl_up(incl, off);
    if (lane >= off) incl += t;
  }
  if (lane == 63) ws[wid] = incl;
  __syncthreads();
  int woff = 0;
  #pragma unroll
  for (int w = 0; w < 4; w++) woff += (w < wid) ? ws[w] : 0;
  *tot_out = ws[0] + ws[1] + ws[2] + ws[3];
  return woff + incl - v;
}

__global__ __launch_bounds__(256) void scanA(const int* __restrict__ cnt,
                                             int* __restrict__ rowptr,
                                             int* __restrict__ blocksum, int n) {
  int i = blockIdx.x * 256 + threadIdx.x;
  int v = (i < n) ? cnt[i] : 0;
  int tot;
  int excl = block_excl_scan_256(v, threadIdx.x, &tot);
  if (i < n) rowptr[i] = excl;
  if (threadIdx.x == 0) blocksum[blockIdx.x] = tot;
}

__global__ __launch_bounds__(256) void scanB(const int* __restrict__ blocksum,
                                             int* __restrict__ blockoff,
                                             int* __restrict__ rowptr, int nb, int n) {
  int tid = threadIdx.x;
  int v = (tid < nb) ? blocksum[tid] : 0;
  int tot;
  int excl = block_excl_scan_256(v, tid, &tot);
  if (tid < nb) blockoff[tid] = excl;
  if (tid == 0) rowptr[n] = tot;
}

__global__ __launch_bounds__(256) void scanC(int* __restrict__ rowptr,
                                             const int* __restrict__ blockoff,
                                             int* __restrict__ cursor, int n) {
  int i = blockIdx.x * 256 + threadIdx.x;
  if (i < n) {
    int r = rowptr[i] + blockoff[blockIdx.x];
    rowptr[i] = r;
    cursor[i] = r;
  }
}

// XCD-range-partitioned CSR fill: same structure as hist_ranged. All csr
// scatter-writes for a node range come from one XCD -> lines fill while
// L2-resident -> ~1 writeback per 64B line instead of ~16.
__global__ __launch_bounds__(256) void fill_ranged(const int* __restrict__ src,
                                                   const int* __restrict__ dst,
                                                   int* __restrict__ cursor,
                                                   int* __restrict__ csr, int E) {
  int r = blockIdx.x & (NRANGE - 1);
  int grp = blockIdx.x >> 3;
  int ngrp = gridDim.x >> 3;
  int lo = r * RANGE_SZ, hi = lo + RANGE_SZ;
  int stride = ngrp * 256;
  int e4n = E / 4;
  for (int i = grp * 256 + threadIdx.x; i < e4n; i += stride) {
    int4 d = *(const int4*)(dst + i * 4);
    int4 s = *(const int4*)(src + i * 4);
    if (d.x >= lo && d.x < hi) csr[atomicAdd(&cursor[d.x], 1)] = s.x;
    if (d.y >= lo && d.y < hi) csr[atomicAdd(&cursor[d.y], 1)] = s.y;
    if (d.z >= lo && d.z < hi) csr[atomicAdd(&cursor[d.z], 1)] = s.z;
    if (d.w >= lo && d.w < hi) csr[atomicAdd(&cursor[d.w], 1)] = s.w;
  }
}

// ---------------- conversions ----------------

__global__ void cvt_x_kernel(const float* __restrict__ x, ushort* __restrict__ xb, int n4) {
  int i = blockIdx.x * blockDim.x + threadIdx.x;
  if (i >= n4) return;
  float4 v = *(const float4*)(x + i * 4);
  ushort u0 = f2bf(v.x), u1 = f2bf(v.y), u2 = f2bf(v.z), u3 = f2bf(v.w);
  ushort4 o = make_ushort4(u0, u1, u2, u3);
  *(ushort4*)(xb + i * 4) = o;
}

// pack [Wl | Wr] (each [K][J2] f32 row-major) into bf16 MFMA-swizzled layout:
// wcat[kk8][j][i] = W[kk8*8+i][j],  j in [0,2*J2)
__global__ void pack_w(const float* __restrict__ Wl, const float* __restrict__ Wr,
                       ushort* __restrict__ wcat, int K, int J2) {
  int idx = blockIdx.x * 256 + threadIdx.x;
  int Jcat = 2 * J2;
  int total = (K / 8) * Jcat;
  if (idx >= total) return;
  int kk8 = idx / Jcat, j = idx % Jcat;
  const float* W = (j < J2) ? Wl : Wr;
  int jj = (j < J2) ? j : j - J2;
  ushort8 v;
  #pragma unroll
  for (int i = 0; i < 8; i++) v[i] = f2bf(W[(kk8 * 8 + i) * J2 + jj]);
  *(ushort8*)(wcat + (size_t)idx * 8) = v;
}

// ---------------- bf16 MFMA GEMM: t = hb @ [Wl|Wr] ----------------
template <int K, int J2>
__global__ __launch_bounds__(256) void gemm_mfma(
    const ushort* __restrict__ hb, const ushort* __restrict__ wcat,
    ushort* __restrict__ tl, ushort* __restrict__ tr, int n) {
  constexpr int Jcat = 2 * J2;
  constexpr int NT = Jcat / 16;
  constexpr int KS = K / 32;
  constexpr int BM = 128;
  constexpr int LDS_US = (BM * Jcat > K * Jcat) ? BM * Jcat : K * Jcat;
  __shared__ ushort lds[LDS_US];

  int tid = threadIdx.x;
  int wid = tid >> 6, lane = tid & 63;
  int row0 = blockIdx.x * BM;

  constexpr int WCH = K * Jcat / 8;
  for (int c = tid; c < WCH; c += 256) {
    *(ushort8*)(lds + c * 8) = *(const ushort8*)(wcat + (size_t)c * 8);
  }
  __syncthreads();

  int rg = lane >> 4, lc = lane & 15;
  int r0 = row0 + wid * 32 + lc;
  int r1 = r0 + 16;
  long ar0 = (long)min(r0, n - 1) * K;
  long ar1 = (long)min(r1, n - 1) * K;

  f32x4 acc[2][NT];
  #pragma unroll
  for (int mt = 0; mt < 2; mt++)
    #pragma unroll
    for (int jt = 0; jt < NT; jt++) acc[mt][jt] = (f32x4){0.f, 0.f, 0.f, 0.f};

  #pragma unroll
  for (int ks = 0; ks < KS; ks++) {
    int koff = ks * 32 + rg * 8;
    short8 a0 = *(const short8*)(hb + ar0 + koff);
    short8 a1 = *(const short8*)(hb + ar1 + koff);
    int kk8 = ks * 4 + rg;
    #pragma unroll
    for (int jt = 0; jt < NT; jt++) {
      short8 b = *(const short8*)(lds + ((size_t)kk8 * Jcat + jt * 16 + lc) * 8);
      acc[0][jt] = __builtin_amdgcn_mfma_f32_16x16x32_bf16(a0, b, acc[0][jt], 0, 0, 0);
      acc[1][jt] = __builtin_amdgcn_mfma_f32_16x16x32_bf16(a1, b, acc[1][jt], 0, 0, 0);
    }
  }
  __syncthreads();

  // C/D layout: col = lane&15, row = (lane>>4)*4 + reg
  #pragma unroll
  for (int mt = 0; mt < 2; mt++) {
    int rbase = wid * 32 + mt * 16 + rg * 4;
    #pragma unroll
    for (int jt = 0; jt < NT; jt++) {
      int col = jt * 16 + lc;
      #pragma unroll
      for (int r = 0; r < 4; r++)
        lds[(size_t)(rbase + r) * Jcat + col] = f2bf(acc[mt][jt][r]);
    }
  }
  __syncthreads();

  constexpr int CPR = J2 / 8;
  for (int i = tid; i < BM * 2 * CPR; i += 256) {
    int row = i / (2 * CPR), cc = i % (2 * CPR);
    int grow = row0 + row;
    if (grow < n) {
      ushort8 v = *(ushort8*)(lds + (size_t)row * Jcat + cc * 8);
      ushort* dstp = (cc < CPR) ? (tl + (size_t)grow * J2 + cc * 8)
                                : (tr + (size_t)grow * J2 + (size_t)(cc - CPR) * 8);
      *(ushort8*)dstp = v;
    }
  }
}

// ---------------- fused aggregate + bias + relu (J2=128) ----------------
__global__ __launch_bounds__(256) void agg_relu128(
    const ushort* __restrict__ tl, const ushort* __restrict__ tr,
    const float* __restrict__ bias,
    const int* __restrict__ rowptr, const int* __restrict__ csr,
    ushort* __restrict__ hout, int n) {
  int node = blockIdx.x * 16 + (threadIdx.x >> 4);
  int lane = threadIdx.x & 15;
  if (node >= n) return;
  int lo = rowptr[node], hi = rowptr[node + 1];

  float s[8];
  #pragma unroll
  for (int i = 0; i < 8; i++) s[i] = 0.f;

  int e = lo;
  for (; e + 1 < hi; e += 2) {
    int i0 = csr[e], i1 = csr[e + 1];
    ushort8 v0 = *(const ushort8*)(tl + (size_t)i0 * 128 + lane * 8);
    ushort8 v1 = *(const ushort8*)(tl + (size_t)i1 * 128 + lane * 8);
    #pragma unroll
    for (int i = 0; i < 8; i++) s[i] += bf2f(v0[i]) + bf2f(v1[i]);
  }
  if (e < hi) {
    ushort8 v0 = *(const ushort8*)(tl + (size_t)csr[e] * 128 + lane * 8);
    #pragma unroll
    for (int i = 0; i < 8; i++) s[i] += bf2f(v0[i]);
  }

  int deg = hi - lo;
  float inv = (deg > 0) ? 1.f / (float)deg : 0.f;
  ushort8 tv = *(const ushort8*)(tr + (size_t)node * 128 + lane * 8);
  float4 b0 = *(const float4*)(bias + lane * 8);
  float4 b1 = *(const float4*)(bias + lane * 8 + 4);
  float bb[8] = {b0.x, b0.y, b0.z, b0.w, b1.x, b1.y, b1.z, b1.w};
  ushort8 o;
  #pragma unroll
  for (int i = 0; i < 8; i++) {
    float v = s[i] * inv + bf2f(tv[i]) + bb[i];
    o[i] = f2bf(v > 0.f ? v : 0.f);
  }
  *(ushort8*)(hout + (size_t)node * 128 + lane * 8) = o;
}

// ---------------- layer 3 aggregate + relu + head (J2=64) ----------------
__global__ __launch_bounds__(256) void agg_head(
    const ushort* __restrict__ tl, const ushort* __restrict__ tr,
    const float* __restrict__ bias, const float* __restrict__ Wc,
    const float* __restrict__ bc,
    const int* __restrict__ rowptr, const int* __restrict__ csr,
    float* __restrict__ out, int n) {
  int node = blockIdx.x * 32 + (threadIdx.x >> 3);
  int lane = threadIdx.x & 7;
  if (node >= n) return;
  int lo = rowptr[node], hi = rowptr[node + 1];

  float s[8];
  #pragma unroll
  for (int i = 0; i < 8; i++) s[i] = 0.f;

  int e = lo;
  for (; e + 1 < hi; e += 2) {
    int i0 = csr[e], i1 = csr[e + 1];
    ushort8 v0 = *(const ushort8*)(tl + (size_t)i0 * 64 + lane * 8);
    ushort8 v1 = *(const ushort8*)(tl + (size_t)i1 * 64 + lane * 8);
    #pragma unroll
    for (int i = 0; i < 8; i++) s[i] += bf2f(v0[i]) + bf2f(v1[i]);
  }
  if (e < hi) {
    ushort8 v0 = *(const ushort8*)(tl + (size_t)csr[e] * 64 + lane * 8);
    #pragma unroll
    for (int i = 0; i < 8; i++) s[i] += bf2f(v0[i]);
  }

  int deg = hi - lo;
  float inv = (deg > 0) ? 1.f / (float)deg : 0.f;
  ushort8 tv = *(const ushort8*)(tr + (size_t)node * 64 + lane * 8);
  float p0 = 0.f, p1 = 0.f;
  #pragma unroll
  for (int i = 0; i < 8; i++) {
    int k = lane * 8 + i;
    float v = s[i] * inv + bf2f(tv[i]) + bias[k];
    v = v > 0.f ? v : 0.f;
    p0 += v * Wc[k * 2 + 0];
    p1 += v * Wc[k * 2 + 1];
  }
  #pragma unroll
  for (int off = 1; off < 8; off <<= 1) {
    p0 += __shfl_xor(p0, off);
    p1 += __shfl_xor(p1, off);
  }
  if (lane == 0) {
    out[(size_t)node * 2 + 0] = p0 + bc[0];
    out[(size_t)node * 2 + 1] = p1 + bc[1];
  }
}

extern "C" void kernel_launch(void* const* d_in, const int* in_sizes, int n_in,
                              void* d_out, int out_size, void* d_ws, size_t ws_size,
                              hipStream_t stream) {
  const float* x   = (const float*)d_in[0];
  const int*   ei  = (const int*)d_in[1];
  const float* Wl1 = (const float*)d_in[2];
  const float* Wr1 = (const float*)d_in[3];
  const float* b1  = (const float*)d_in[4];
  const float* Wl2 = (const float*)d_in[5];
  const float* Wr2 = (const float*)d_in[6];
  const float* b2  = (const float*)d_in[7];
  const float* Wl3 = (const float*)d_in[8];
  const float* Wr3 = (const float*)d_in[9];
  const float* b3  = (const float*)d_in[10];
  const float* Wc  = (const float*)d_in[11];
  const float* bc  = (const float*)d_in[12];
  float* out = (float*)d_out;

  const int* src = ei;
  const int* dst = ei + N_EDGES;

  char* ws = (char*)d_ws;
  size_t off = 0;
  auto alloc = [&](size_t bytes) -> void* {
    void* p = ws + off;
    off += (bytes + 255) & ~(size_t)255;
    return p;
  };
  int*    rowptr   = (int*)alloc((N_NODES + 1) * sizeof(int));
  int*    cnt      = (int*)alloc(N_NODES * sizeof(int));
  int*    cursor   = (int*)alloc(N_NODES * sizeof(int));
  int*    csr      = (int*)alloc(N_EDGES * sizeof(int));
  int*    blocksum = (int*)alloc(256 * sizeof(int));
  int*    blockoff = (int*)alloc(256 * sizeof(int));
  ushort* xb       = (ushort*)alloc((size_t)N_NODES * 96 * 2);
  ushort* wcat1    = (ushort*)alloc((size_t)96 * 256 * 2);
  ushort* wcat2    = (ushort*)alloc((size_t)128 * 256 * 2);
  ushort* wcat3    = (ushort*)alloc((size_t)128 * 128 * 2);
  ushort* tl       = (ushort*)alloc((size_t)N_NODES * 128 * 2);
  ushort* tr       = (ushort*)alloc((size_t)N_NODES * 128 * 2);
  ushort* hA       = (ushort*)alloc((size_t)N_NODES * 128 * 2);
  ushort* hB       = (ushort*)alloc((size_t)N_NODES * 128 * 2);
  (void)ws_size; (void)n_in; (void)in_sizes; (void)out_size;

  // CSR build (XCD-range-partitioned hist + fill)
  zero_i32<<<(N_NODES + 255) / 256, 256, 0, stream>>>(cnt, N_NODES);
  hist_ranged<<<CSR_BLOCKS, 256, 0, stream>>>(dst, cnt, N_EDGES);
  scanA<<<SCAN_NB, 256, 0, stream>>>(cnt, rowptr, blocksum, N_NODES);
  scanB<<<1, 256, 0, stream>>>(blocksum, blockoff, rowptr, SCAN_NB, N_NODES);
  scanC<<<SCAN_NB, 256, 0, stream>>>(rowptr, blockoff, cursor, N_NODES);
  fill_ranged<<<CSR_BLOCKS, 256, 0, stream>>>(src, dst, cursor, csr, N_EDGES);

  // conversions
  cvt_x_kernel<<<(N_NODES * 96 / 4 + 255) / 256, 256, 0, stream>>>(x, xb, N_NODES * 96 / 4);
  pack_w<<<(12 * 256 + 255) / 256, 256, 0, stream>>>(Wl1, Wr1, wcat1, 96, 128);
  pack_w<<<(16 * 256 + 255) / 256, 256, 0, stream>>>(Wl2, Wr2, wcat2, 128, 128);
  pack_w<<<(16 * 128 + 255) / 256, 256, 0, stream>>>(Wl3, Wr3, wcat3, 128, 64);

  const int gemm_grid = (N_NODES + 127) / 128;
  const int agg_grid  = (N_NODES + 15) / 16;
  const int head_grid = (N_NODES + 31) / 32;

  gemm_mfma<96, 128><<<gemm_grid, 256, 0, stream>>>(xb, wcat1, tl, tr, N_NODES);
  agg_relu128<<<agg_grid, 256, 0, stream>>>(tl, tr, b1, rowptr, csr, hA, N_NODES);
  gemm_mfma<128, 128><<<gemm_grid, 256, 0, stream>>>(hA, wcat2, tl, tr, N_NODES);
  agg_relu128<<<agg_grid, 256, 0, stream>>>(tl, tr, b2, rowptr, csr, hB, N_NODES);
  gemm_mfma<128, 64><<<gemm_grid, 256, 0, stream>>>(hB, wcat3, tl, tr, N_NODES);
  agg_head<<<head_grid, 256, 0, stream>>>(tl, tr, b3, Wc, bc, rowptr, csr, out, N_NODES);
}

// Round 5
// 219.384 us; speedup vs baseline: 2.6539x; 1.0220x over previous
//
#include <hip/hip_runtime.h>

#define N_NODES 50000
#define N_EDGES 800000
#define SCAN_NB ((N_NODES + 255) / 256)
#define NRANGE 8
#define RANGE_SZ ((N_NODES + NRANGE - 1) / NRANGE)   // 6250
#define CSR_BLOCKS 2048

typedef __attribute__((ext_vector_type(8))) short short8;
typedef __attribute__((ext_vector_type(8))) unsigned short ushort8;
typedef __attribute__((ext_vector_type(4))) float f32x4;

__device__ __forceinline__ float bf2f(unsigned short u) {
  unsigned int x = ((unsigned int)u) << 16;
  return __builtin_bit_cast(float, x);
}
__device__ __forceinline__ unsigned short f2bf(float f) {
  unsigned int x = __builtin_bit_cast(unsigned int, f);
  unsigned int r = x + 0x7FFFu + ((x >> 16) & 1u);
  return (unsigned short)(r >> 16);
}

// ---------------- CSR construction ----------------

// Replicated histogram: copy c = bid&7 lands on XCD c (round-robin dispatch
// heuristic) -> atomics confined to a 200KB XCD-local L2 window. Single pass.
__global__ __launch_bounds__(256) void hist8(const int* __restrict__ dst,
                                             int* __restrict__ cnt8, int e4n) {
  int i = blockIdx.x * 256 + threadIdx.x;
  int* cnt = cnt8 + (size_t)(blockIdx.x & 7) * N_NODES;
  if (i < e4n) {
    int4 d = *(const int4*)(dst + i * 4);
    atomicAdd(&cnt[d.x], 1);
    atomicAdd(&cnt[d.y], 1);
    atomicAdd(&cnt[d.z], 1);
    atomicAdd(&cnt[d.w], 1);
  }
}

__device__ __forceinline__ int block_excl_scan_256(int v, int tid, int* tot_out) {
  __shared__ int ws[4];
  int lane = tid & 63, wid = tid >> 6;
  int incl = v;
  #pragma unroll
  for (int off = 1; off < 64; off <<= 1) {
    int t = __shfl_up(incl, off);
    if (lane >= off) incl += t;
  }
  if (lane == 63) ws[wid] = incl;
  __syncthreads();
  int woff = 0;
  #pragma unroll
  for (int w = 0; w < 4; w++) woff += (w < wid) ? ws[w] : 0;
  *tot_out = ws[0] + ws[1] + ws[2] + ws[3];
  return woff + incl - v;
}

// stage A: sum the 8 histogram copies + per-block exclusive scan
__global__ __launch_bounds__(256) void scanA(const int* __restrict__ cnt8,
                                             int* __restrict__ rowptr,
                                             int* __restrict__ blocksum, int n) {
  int i = blockIdx.x * 256 + threadIdx.x;
  int v = 0;
  if (i < n) {
    #pragma unroll
    for (int c = 0; c < 8; c++) v += cnt8[(size_t)c * N_NODES + i];
  }
  int tot;
  int excl = block_excl_scan_256(v, threadIdx.x, &tot);
  if (i < n) rowptr[i] = excl;
  if (threadIdx.x == 0) blocksum[blockIdx.x] = tot;
}

__global__ __launch_bounds__(256) void scanB(const int* __restrict__ blocksum,
                                             int* __restrict__ blockoff,
                                             int* __restrict__ rowptr, int nb, int n) {
  int tid = threadIdx.x;
  int v = (tid < nb) ? blocksum[tid] : 0;
  int tot;
  int excl = block_excl_scan_256(v, tid, &tot);
  if (tid < nb) blockoff[tid] = excl;
  if (tid == 0) rowptr[n] = tot;
}

__global__ __launch_bounds__(256) void scanC(int* __restrict__ rowptr,
                                             const int* __restrict__ blockoff,
                                             int* __restrict__ cursor, int n) {
  int i = blockIdx.x * 256 + threadIdx.x;
  if (i < n) {
    int r = rowptr[i] + blockoff[blockIdx.x];
    rowptr[i] = r;
    cursor[i] = r;
  }
}

// XCD-range-partitioned CSR fill, ushort entries (src < 65536).
__global__ __launch_bounds__(256) void fill_ranged(const int* __restrict__ src,
                                                   const int* __restrict__ dst,
                                                   int* __restrict__ cursor,
                                                   ushort* __restrict__ csr, int E) {
  int r = blockIdx.x & (NRANGE - 1);
  int grp = blockIdx.x >> 3;
  int ngrp = gridDim.x >> 3;
  int lo = r * RANGE_SZ, hi = lo + RANGE_SZ;
  int stride = ngrp * 256;
  int e4n = E / 4;
  for (int i = grp * 256 + threadIdx.x; i < e4n; i += stride) {
    int4 d = *(const int4*)(dst + i * 4);
    int4 s = *(const int4*)(src + i * 4);
    if (d.x >= lo && d.x < hi) csr[atomicAdd(&cursor[d.x], 1)] = (ushort)s.x;
    if (d.y >= lo && d.y < hi) csr[atomicAdd(&cursor[d.y], 1)] = (ushort)s.y;
    if (d.z >= lo && d.z < hi) csr[atomicAdd(&cursor[d.z], 1)] = (ushort)s.z;
    if (d.w >= lo && d.w < hi) csr[atomicAdd(&cursor[d.w], 1)] = (ushort)s.w;
  }
}

// ---------------- conversions ----------------

__global__ void cvt_x_kernel(const float* __restrict__ x, ushort* __restrict__ xb, int n4) {
  int i = blockIdx.x * blockDim.x + threadIdx.x;
  if (i >= n4) return;
  float4 v = *(const float4*)(x + i * 4);
  ushort u0 = f2bf(v.x), u1 = f2bf(v.y), u2 = f2bf(v.z), u3 = f2bf(v.w);
  ushort4 o = make_ushort4(u0, u1, u2, u3);
  *(ushort4*)(xb + i * 4) = o;
}

// pack [Wl | Wr] (each [K][J2] f32 row-major) into bf16 MFMA layout:
// wcat[kk8][j][i] = W[kk8*8+i][j]
__global__ void pack_w(const float* __restrict__ Wl, const float* __restrict__ Wr,
                       ushort* __restrict__ wcat, int K, int J2) {
  int idx = blockIdx.x * 256 + threadIdx.x;
  int Jcat = 2 * J2;
  int total = (K / 8) * Jcat;
  if (idx >= total) return;
  int kk8 = idx / Jcat, j = idx % Jcat;
  const float* W = (j < J2) ? Wl : Wr;
  int jj = (j < J2) ? j : j - J2;
  ushort8 v;
  #pragma unroll
  for (int i = 0; i < 8; i++) v[i] = f2bf(W[(kk8 * 8 + i) * J2 + jj]);
  *(ushort8*)(wcat + (size_t)idx * 8) = v;
}

// ---------------- bf16 MFMA GEMM: t = hb @ [Wl|Wr] ----------------
template <int K, int J2>
__global__ __launch_bounds__(256) void gemm_mfma(
    const ushort* __restrict__ hb, const ushort* __restrict__ wcat,
    ushort* __restrict__ tl, ushort* __restrict__ tr, int n) {
  constexpr int Jcat = 2 * J2;
  constexpr int NT = Jcat / 16;
  constexpr int KS = K / 32;
  constexpr int BM = 128;
  constexpr int LDS_US = (BM * Jcat > K * Jcat) ? BM * Jcat : K * Jcat;
  __shared__ ushort lds[LDS_US];

  int tid = threadIdx.x;
  int wid = tid >> 6, lane = tid & 63;
  int row0 = blockIdx.x * BM;

  constexpr int WCH = K * Jcat / 8;
  for (int c = tid; c < WCH; c += 256) {
    *(ushort8*)(lds + c * 8) = *(const ushort8*)(wcat + (size_t)c * 8);
  }
  __syncthreads();

  int rg = lane >> 4, lc = lane & 15;
  int r0 = row0 + wid * 32 + lc;
  int r1 = r0 + 16;
  long ar0 = (long)min(r0, n - 1) * K;
  long ar1 = (long)min(r1, n - 1) * K;

  f32x4 acc[2][NT];
  #pragma unroll
  for (int mt = 0; mt < 2; mt++)
    #pragma unroll
    for (int jt = 0; jt < NT; jt++) acc[mt][jt] = (f32x4){0.f, 0.f, 0.f, 0.f};

  #pragma unroll
  for (int ks = 0; ks < KS; ks++) {
    int koff = ks * 32 + rg * 8;
    short8 a0 = *(const short8*)(hb + ar0 + koff);
    short8 a1 = *(const short8*)(hb + ar1 + koff);
    int kk8 = ks * 4 + rg;
    #pragma unroll
    for (int jt = 0; jt < NT; jt++) {
      short8 b = *(const short8*)(lds + ((size_t)kk8 * Jcat + jt * 16 + lc) * 8);
      acc[0][jt] = __builtin_amdgcn_mfma_f32_16x16x32_bf16(a0, b, acc[0][jt], 0, 0, 0);
      acc[1][jt] = __builtin_amdgcn_mfma_f32_16x16x32_bf16(a1, b, acc[1][jt], 0, 0, 0);
    }
  }
  __syncthreads();

  // C/D layout: col = lane&15, row = (lane>>4)*4 + reg
  #pragma unroll
  for (int mt = 0; mt < 2; mt++) {
    int rbase = wid * 32 + mt * 16 + rg * 4;
    #pragma unroll
    for (int jt = 0; jt < NT; jt++) {
      int col = jt * 16 + lc;
      #pragma unroll
      for (int r = 0; r < 4; r++)
        lds[(size_t)(rbase + r) * Jcat + col] = f2bf(acc[mt][jt][r]);
    }
  }
  __syncthreads();

  constexpr int CPR = J2 / 8;
  for (int i = tid; i < BM * 2 * CPR; i += 256) {
    int row = i / (2 * CPR), cc = i % (2 * CPR);
    int grow = row0 + row;
    if (grow < n) {
      ushort8 v = *(ushort8*)(lds + (size_t)row * Jcat + cc * 8);
      ushort* dstp = (cc < CPR) ? (tl + (size_t)grow * J2 + cc * 8)
                                : (tr + (size_t)grow * J2 + (size_t)(cc - CPR) * 8);
      *(ushort8*)dstp = v;
    }
  }
}

// ---------------- fused aggregate + bias + relu (J2=128) ----------------
__global__ __launch_bounds__(256) void agg_relu128(
    const ushort* __restrict__ tl, const ushort* __restrict__ tr,
    const float* __restrict__ bias,
    const int* __restrict__ rowptr, const ushort* __restrict__ csr,
    ushort* __restrict__ hout, int n) {
  int node = blockIdx.x * 16 + (threadIdx.x >> 4);
  int lane = threadIdx.x & 15;
  if (node >= n) return;
  int lo = rowptr[node], hi = rowptr[node + 1];

  float s[8];
  #pragma unroll
  for (int i = 0; i < 8; i++) s[i] = 0.f;

  int e = lo;
  for (; e + 1 < hi; e += 2) {
    int i0 = csr[e], i1 = csr[e + 1];
    ushort8 v0 = *(const ushort8*)(tl + (size_t)i0 * 128 + lane * 8);
    ushort8 v1 = *(const ushort8*)(tl + (size_t)i1 * 128 + lane * 8);
    #pragma unroll
    for (int i = 0; i < 8; i++) s[i] += bf2f(v0[i]) + bf2f(v1[i]);
  }
  if (e < hi) {
    ushort8 v0 = *(const ushort8*)(tl + (size_t)csr[e] * 128 + lane * 8);
    #pragma unroll
    for (int i = 0; i < 8; i++) s[i] += bf2f(v0[i]);
  }

  int deg = hi - lo;
  float inv = (deg > 0) ? 1.f / (float)deg : 0.f;
  ushort8 tv = *(const ushort8*)(tr + (size_t)node * 128 + lane * 8);
  float4 b0 = *(const float4*)(bias + lane * 8);
  float4 b1 = *(const float4*)(bias + lane * 8 + 4);
  float bb[8] = {b0.x, b0.y, b0.z, b0.w, b1.x, b1.y, b1.z, b1.w};
  ushort8 o;
  #pragma unroll
  for (int i = 0; i < 8; i++) {
    float v = s[i] * inv + bf2f(tv[i]) + bb[i];
    o[i] = f2bf(v > 0.f ? v : 0.f);
  }
  *(ushort8*)(hout + (size_t)node * 128 + lane * 8) = o;
}

// ---------------- layer 3 aggregate + relu + head (J2=64) ----------------
__global__ __launch_bounds__(256) void agg_head(
    const ushort* __restrict__ tl, const ushort* __restrict__ tr,
    const float* __restrict__ bias, const float* __restrict__ Wc,
    const float* __restrict__ bc,
    const int* __restrict__ rowptr, const ushort* __restrict__ csr,
    float* __restrict__ out, int n) {
  int node = blockIdx.x * 32 + (threadIdx.x >> 3);
  int lane = threadIdx.x & 7;
  if (node >= n) return;
  int lo = rowptr[node], hi = rowptr[node + 1];

  float s[8];
  #pragma unroll
  for (int i = 0; i < 8; i++) s[i] = 0.f;

  int e = lo;
  for (; e + 1 < hi; e += 2) {
    int i0 = csr[e], i1 = csr[e + 1];
    ushort8 v0 = *(const ushort8*)(tl + (size_t)i0 * 64 + lane * 8);
    ushort8 v1 = *(const ushort8*)(tl + (size_t)i1 * 64 + lane * 8);
    #pragma unroll
    for (int i = 0; i < 8; i++) s[i] += bf2f(v0[i]) + bf2f(v1[i]);
  }
  if (e < hi) {
    ushort8 v0 = *(const ushort8*)(tl + (size_t)csr[e] * 64 + lane * 8);
    #pragma unroll
    for (int i = 0; i < 8; i++) s[i] += bf2f(v0[i]);
  }

  int deg = hi - lo;
  float inv = (deg > 0) ? 1.f / (float)deg : 0.f;
  ushort8 tv = *(const ushort8*)(tr + (size_t)node * 64 + lane * 8);
  float p0 = 0.f, p1 = 0.f;
  #pragma unroll
  for (int i = 0; i < 8; i++) {
    int k = lane * 8 + i;
    float v = s[i] * inv + bf2f(tv[i]) + bias[k];
    v = v > 0.f ? v : 0.f;
    p0 += v * Wc[k * 2 + 0];
    p1 += v * Wc[k * 2 + 1];
  }
  #pragma unroll
  for (int off = 1; off < 8; off <<= 1) {
    p0 += __shfl_xor(p0, off);
    p1 += __shfl_xor(p1, off);
  }
  if (lane == 0) {
    out[(size_t)node * 2 + 0] = p0 + bc[0];
    out[(size_t)node * 2 + 1] = p1 + bc[1];
  }
}

extern "C" void kernel_launch(void* const* d_in, const int* in_sizes, int n_in,
                              void* d_out, int out_size, void* d_ws, size_t ws_size,
                              hipStream_t stream) {
  const float* x   = (const float*)d_in[0];
  const int*   ei  = (const int*)d_in[1];
  const float* Wl1 = (const float*)d_in[2];
  const float* Wr1 = (const float*)d_in[3];
  const float* b1  = (const float*)d_in[4];
  const float* Wl2 = (const float*)d_in[5];
  const float* Wr2 = (const float*)d_in[6];
  const float* b2  = (const float*)d_in[7];
  const float* Wl3 = (const float*)d_in[8];
  const float* Wr3 = (const float*)d_in[9];
  const float* b3  = (const float*)d_in[10];
  const float* Wc  = (const float*)d_in[11];
  const float* bc  = (const float*)d_in[12];
  float* out = (float*)d_out;

  const int* src = ei;
  const int* dst = ei + N_EDGES;

  char* ws = (char*)d_ws;
  size_t off = 0;
  auto alloc = [&](size_t bytes) -> void* {
    void* p = ws + off;
    off += (bytes + 255) & ~(size_t)255;
    return p;
  };
  int*    rowptr   = (int*)alloc((N_NODES + 1) * sizeof(int));
  int*    cnt8     = (int*)alloc((size_t)8 * N_NODES * sizeof(int));
  int*    cursor   = (int*)alloc(N_NODES * sizeof(int));
  ushort* csr      = (ushort*)alloc(N_EDGES * sizeof(ushort));
  int*    blocksum = (int*)alloc(256 * sizeof(int));
  int*    blockoff = (int*)alloc(256 * sizeof(int));
  ushort* xb       = (ushort*)alloc((size_t)N_NODES * 96 * 2);
  ushort* wcat1    = (ushort*)alloc((size_t)96 * 256 * 2);
  ushort* wcat2    = (ushort*)alloc((size_t)128 * 256 * 2);
  ushort* wcat3    = (ushort*)alloc((size_t)128 * 128 * 2);
  ushort* tl       = (ushort*)alloc((size_t)N_NODES * 128 * 2);
  ushort* tr       = (ushort*)alloc((size_t)N_NODES * 128 * 2);
  ushort* hA       = (ushort*)alloc((size_t)N_NODES * 128 * 2);
  ushort* hB       = (ushort*)alloc((size_t)N_NODES * 128 * 2);
  (void)ws_size; (void)n_in; (void)in_sizes; (void)out_size;

  // CSR build
  hipMemsetAsync(cnt8, 0, (size_t)8 * N_NODES * sizeof(int), stream);
  hist8<<<(N_EDGES / 4 + 255) / 256, 256, 0, stream>>>(dst, cnt8, N_EDGES / 4);
  scanA<<<SCAN_NB, 256, 0, stream>>>(cnt8, rowptr, blocksum, N_NODES);
  scanB<<<1, 256, 0, stream>>>(blocksum, blockoff, rowptr, SCAN_NB, N_NODES);
  scanC<<<SCAN_NB, 256, 0, stream>>>(rowptr, blockoff, cursor, N_NODES);
  fill_ranged<<<CSR_BLOCKS, 256, 0, stream>>>(src, dst, cursor, csr, N_EDGES);

  // conversions
  cvt_x_kernel<<<(N_NODES * 96 / 4 + 255) / 256, 256, 0, stream>>>(x, xb, N_NODES * 96 / 4);
  pack_w<<<(12 * 256 + 255) / 256, 256, 0, stream>>>(Wl1, Wr1, wcat1, 96, 128);
  pack_w<<<(16 * 256 + 255) / 256, 256, 0, stream>>>(Wl2, Wr2, wcat2, 128, 128);
  pack_w<<<(16 * 128 + 255) / 256, 256, 0, stream>>>(Wl3, Wr3, wcat3, 128, 64);

  const int gemm_grid = (N_NODES + 127) / 128;
  const int agg_grid  = (N_NODES + 15) / 16;
  const int head_grid = (N_NODES + 31) / 32;

  gemm_mfma<96, 128><<<gemm_grid, 256, 0, stream>>>(xb, wcat1, tl, tr, N_NODES);
  agg_relu128<<<agg_grid, 256, 0, stream>>>(tl, tr, b1, rowptr, csr, hA, N_NODES);
  gemm_mfma<128, 128><<<gemm_grid, 256, 0, stream>>>(hA, wcat2, tl, tr, N_NODES);
  agg_relu128<<<agg_grid, 256, 0, stream>>>(tl, tr, b2, rowptr, csr, hB, N_NODES);
  gemm_mfma<128, 64><<<gemm_grid, 256, 0, stream>>>(hB, wcat3, tl, tr, N_NODES);
  agg_head<<<head_grid, 256, 0, stream>>>(tl, tr, b3, Wc, bc, rowptr, csr, out, N_NODES);
}